// Round 1
// baseline (281.601 us; speedup 1.0000x reference)
//
#include <hip/hip_runtime.h>
#include <hip/hip_bf16.h>
#include <stdint.h>

#define T_SEQ 4096
#define NH 12
#define HD 64
#define ED 768
#define N_QKV 2304

typedef short bf16x8 __attribute__((ext_vector_type(8)));
typedef float f32x4 __attribute__((ext_vector_type(4)));
typedef unsigned short u16x4 __attribute__((ext_vector_type(4)));

__device__ __forceinline__ unsigned short f2bf(float f) {
  unsigned int u = __float_as_uint(f);
  unsigned int r = (u + 0x7FFFu + ((u >> 16) & 1u)) >> 16;
  return (unsigned short)r;
}

// ---------------- convert: f32 -> bf16 for x, Wqkv(concat), Wo; bias concat ----
__global__ void convert_kernel(const float* __restrict__ x,
                               const float* __restrict__ wq, const float* __restrict__ wk,
                               const float* __restrict__ wv, const float* __restrict__ wo,
                               const float* __restrict__ bq, const float* __restrict__ bk,
                               const float* __restrict__ bv,
                               unsigned short* __restrict__ xb, unsigned short* __restrict__ wb,
                               unsigned short* __restrict__ wob, float* __restrict__ biasc)
{
  const int NX = T_SEQ * ED;   // 3145728
  const int NW = ED * ED;      // 589824
  int i = blockIdx.x * blockDim.x + threadIdx.x;
  if (i < NX) { xb[i] = f2bf(x[i]); return; }
  i -= NX;
  if (i < 3 * NW) {
    const float* w = (i < NW) ? wq : ((i < 2 * NW) ? wk : wv);
    wb[i] = f2bf(w[i % NW]);
    return;
  }
  i -= 3 * NW;
  if (i < NW) { wob[i] = f2bf(wo[i]); return; }
  i -= NW;
  if (i < N_QKV) {
    biasc[i] = (i < ED) ? bq[i] : ((i < 2 * ED) ? bk[i - ED] : bv[i - 2 * ED]);
  }
}

// ---------------- bf16 NT GEMM: C[M][ldc] = A[M][K] * B[N][K]^T + bias ---------
// 128x128 tile, BK=64, 4 waves (2x2), each wave 64x64 via 4x4 16x16x32 MFMA frags.
// LDS rows are 128B with 16B-slot XOR swizzle (slot ^= row&7) -> 2-way-free reads.
__global__ __launch_bounds__(256) void gemm_bf16nt(const unsigned short* __restrict__ A,
                                                   const unsigned short* __restrict__ B,
                                                   const float* __restrict__ bias,
                                                   float* __restrict__ C,
                                                   int M, int N, int K, int ldc)
{
  __shared__ unsigned short As[128 * 64];
  __shared__ unsigned short Bs[128 * 64];
  int nb = N >> 7;
  int mt = blockIdx.x / nb, nt = blockIdx.x % nb;
  int m0 = mt << 7, n0 = nt << 7;
  int tid = threadIdx.x;
  int w = tid >> 6, lane = tid & 63;
  int g = lane >> 4, q15 = lane & 15;
  int wm = w >> 1, wn = w & 1;

  f32x4 acc[4][4] = {};

  int nK = K >> 6;
  for (int kt = 0; kt < nK; ++kt) {
    int k0 = kt << 6;
    bf16x8 st[8];
#pragma unroll
    for (int rc = 0; rc < 8; ++rc) {
      int c = rc * 4 + w;                 // 0..31 (16 A-chunks, 16 B-chunks of 1KB)
      int lb = (c & 15) * 1024 + lane * 16;
      int row = lb >> 7, s = (lb >> 4) & 7;
      const unsigned short* src = (c < 16)
          ? (A + (size_t)(m0 + row) * K + k0 + s * 8)
          : (B + (size_t)(n0 + row) * K + k0 + s * 8);
      st[rc] = *(const bf16x8*)src;
    }
    __syncthreads();                       // previous compute done
#pragma unroll
    for (int rc = 0; rc < 8; ++rc) {
      int c = rc * 4 + w;
      int lb = (c & 15) * 1024 + lane * 16;
      int row = lb >> 7, s = (lb >> 4) & 7;
      unsigned short* dstb = (c < 16) ? As : Bs;
      *(bf16x8*)((char*)dstb + row * 128 + ((s ^ (row & 7)) << 4)) = st[rc];
    }
    __syncthreads();
#pragma unroll
    for (int h = 0; h < 2; ++h) {
      bf16x8 af[4], bfr[4];
#pragma unroll
      for (int i = 0; i < 4; ++i) {
        int row = wm * 64 + i * 16 + q15;
        af[i] = *(const bf16x8*)((const char*)As + row * 128 + (((4 * h + g) ^ (row & 7)) << 4));
        int col = wn * 64 + i * 16 + q15;
        bfr[i] = *(const bf16x8*)((const char*)Bs + col * 128 + (((4 * h + g) ^ (col & 7)) << 4));
      }
#pragma unroll
      for (int i = 0; i < 4; ++i)
#pragma unroll
        for (int j = 0; j < 4; ++j)
          acc[i][j] = __builtin_amdgcn_mfma_f32_16x16x32_bf16(af[i], bfr[j], acc[i][j], 0, 0, 0);
    }
  }
#pragma unroll
  for (int j = 0; j < 4; ++j) {
    int col = n0 + wn * 64 + j * 16 + q15;
    float bv = bias[col];
#pragma unroll
    for (int i = 0; i < 4; ++i) {
      int rowb = m0 + wm * 64 + i * 16 + 4 * g;
#pragma unroll
      for (int r = 0; r < 4; ++r)
        C[(size_t)(rowb + r) * ldc + col] = acc[i][j][r] + bv;
    }
  }
}

// ---------------- RoPE (+optional 1/8 scale folded into Q), f32 -> bf16 --------
__global__ void rope_kernel(const float* __restrict__ qkvf, unsigned short* __restrict__ dst,
                            int col0, float scale)
{
  int gid = blockIdx.x * blockDim.x + threadIdx.x;  // 12*4096*32
  int idx = gid & 31;
  int t = (gid >> 5) & (T_SEQ - 1);
  int head = gid >> 17;
  if (head >= NH) return;
  const float* src = qkvf + (size_t)t * N_QKV + col0 + head * HD;
  float x1 = src[idx], x2 = src[idx + 32];
  float inv = exp2f((float)idx * (-13.287712379549449f / 32.0f));  // 10000^(-idx/32)
  float ang = (float)t * inv;
  float s, c;
  sincosf(ang, &s, &c);
  unsigned short* o = dst + ((size_t)head * T_SEQ + t) * HD + idx;
  o[0]  = f2bf((x1 * c - x2 * s) * scale);
  o[32] = f2bf((x1 * s + x2 * c) * scale);
}

// ---------------- V transpose per head: [t][d] f32 -> [d][t] bf16 --------------
__global__ void vtrans_kernel(const float* __restrict__ qkvf, unsigned short* __restrict__ vT)
{
  __shared__ unsigned short tile[64][65];
  int head = blockIdx.x >> 6;
  int t0 = (blockIdx.x & 63) << 6;
  int tid = threadIdx.x;
  int colh = tid & 63, rr = tid >> 6;
#pragma unroll
  for (int i = 0; i < 16; ++i) {
    int row = rr * 16 + i;
    float v = qkvf[(size_t)(t0 + row) * N_QKV + 2 * ED + head * HD + colh];
    tile[colh][row] = f2bf(v);
  }
  __syncthreads();
#pragma unroll
  for (int i = 0; i < 16; ++i) {
    int d = rr * 16 + i;
    vT[((size_t)head * HD + d) * T_SEQ + t0 + colh] = tile[d][colh];
  }
}

// ---------------- Flash attention ---------------------------------------------
// Block = 1 head x 64 queries, 4 waves x 16 q-rows. KV tile = 64 keys.
// S^T = mfma(K, Q): lane holds S[key=16*t16+4g+r][q=lane&15] -> row-local softmax.
// P staged via swizzled LDS -> A-operand of PV. V^T tile gives contiguous B-frags.
__global__ __launch_bounds__(256) void attn_kernel(const unsigned short* __restrict__ qr,
                                                   const unsigned short* __restrict__ kr,
                                                   const unsigned short* __restrict__ vT,
                                                   const float* __restrict__ mask,
                                                   unsigned short* __restrict__ ctx)
{
  __shared__ unsigned short Ks[64 * 64];
  __shared__ unsigned short Vs[64 * 64];
  __shared__ unsigned short Ps[4][1024];
  __shared__ float msk[64];

  int head = blockIdx.x >> 6;
  int qb = blockIdx.x & 63;
  int tid = threadIdx.x;
  int w = tid >> 6, lane = tid & 63;
  int g = lane >> 4, q15 = lane & 15;
  int qw = qb * 64 + w * 16;

  const unsigned short* qbase = qr + ((size_t)head * T_SEQ + qw + q15) * HD + g * 8;
  bf16x8 qf0 = *(const bf16x8*)(qbase);
  bf16x8 qf1 = *(const bf16x8*)(qbase + 32);

  f32x4 cacc[4] = {};
  float m_run = -1e30f, l_run = 0.f;

  for (int kv = 0; kv < T_SEQ / 64; ++kv) {
    int k0 = kv * 64;
    bf16x8 st[4];
#pragma unroll
    for (int rc = 0; rc < 4; ++rc) {
      int c = rc * 4 + w;                  // 0..15: 8 K-chunks then 8 V-chunks
      int lb = (c & 7) * 1024 + lane * 16;
      int row = lb >> 7, s = (lb >> 4) & 7;
      const unsigned short* src = (c < 8)
          ? (kr + ((size_t)head * T_SEQ + k0 + row) * HD + s * 8)
          : (vT + ((size_t)head * HD + row) * T_SEQ + k0 + s * 8);
      st[rc] = *(const bf16x8*)src;
    }
    float mv = (tid < 64) ? mask[k0 + tid] : 0.f;
    __syncthreads();                        // all waves done with prev tile
#pragma unroll
    for (int rc = 0; rc < 4; ++rc) {
      int c = rc * 4 + w;
      int lb = (c & 7) * 1024 + lane * 16;
      int row = lb >> 7, s = (lb >> 4) & 7;
      unsigned short* dstb = (c < 8) ? Ks : Vs;
      *(bf16x8*)((char*)dstb + row * 128 + ((s ^ (row & 7)) << 4)) = st[rc];
    }
    if (tid < 64) msk[tid] = mv;
    __syncthreads();

    // S^T = K(16key x 64d) . Q^T(64d x 16q), 4 key-tiles
    f32x4 sa[4];
#pragma unroll
    for (int t16 = 0; t16 < 4; ++t16) {
      int key = t16 * 16 + q15;
      const char* kb = (const char*)Ks + key * 128;
      bf16x8 a0 = *(const bf16x8*)(kb + ((g ^ (key & 7)) << 4));
      bf16x8 a1 = *(const bf16x8*)(kb + (((4 + g) ^ (key & 7)) << 4));
      f32x4 z = {};
      z = __builtin_amdgcn_mfma_f32_16x16x32_bf16(a0, qf0, z, 0, 0, 0);
      z = __builtin_amdgcn_mfma_f32_16x16x32_bf16(a1, qf1, z, 0, 0, 0);
      sa[t16] = z;
    }

    // online softmax over this tile's 64 keys (per q = lane&15)
    float sv[16];
    float tm = -1e30f;
#pragma unroll
    for (int t16 = 0; t16 < 4; ++t16)
#pragma unroll
      for (int r = 0; r < 4; ++r) {
        float v = sa[t16][r] + (1.0f - msk[t16 * 16 + 4 * g + r]) * (-1e9f);
        sv[t16 * 4 + r] = v;
        tm = fmaxf(tm, v);
      }
    tm = fmaxf(tm, __shfl_xor(tm, 16));
    tm = fmaxf(tm, __shfl_xor(tm, 32));
    float m_new = fmaxf(m_run, tm);
    float alpha = __expf(m_run - m_new);
    float ts = 0.f;
#pragma unroll
    for (int i = 0; i < 16; ++i) { float p = __expf(sv[i] - m_new); sv[i] = p; ts += p; }
    ts += __shfl_xor(ts, 16);
    ts += __shfl_xor(ts, 32);
    l_run = l_run * alpha + ts;
    m_run = m_new;
    float af[4];
#pragma unroll
    for (int r = 0; r < 4; ++r) af[r] = __shfl(alpha, 4 * g + r);
#pragma unroll
    for (int dt = 0; dt < 4; ++dt)
#pragma unroll
      for (int r = 0; r < 4; ++r) cacc[dt][r] *= af[r];

    // P (bf16) -> per-wave LDS, laid out so slot s16 holds keys [8*s16, 8*s16+8)
    char* pw = (char*)Ps[w] + q15 * 128;
#pragma unroll
    for (int t16 = 0; t16 < 4; ++t16) {
      u16x4 pk;
      pk[0] = f2bf(sv[t16 * 4 + 0]);
      pk[1] = f2bf(sv[t16 * 4 + 1]);
      pk[2] = f2bf(sv[t16 * 4 + 2]);
      pk[3] = f2bf(sv[t16 * 4 + 3]);
      int s16 = 2 * t16 + (g >> 1);
      *(u16x4*)(pw + ((s16 ^ (q15 & 7)) << 4) + ((g & 1) << 3)) = pk;
    }

    // PV: ctx[16q][64d] += P(16q x 64key) . V(64key x 64d)
#pragma unroll
    for (int h = 0; h < 2; ++h) {
      bf16x8 pa = *(const bf16x8*)((const char*)Ps[w] + q15 * 128 +
                                   (((4 * h + g) ^ (q15 & 7)) << 4));
#pragma unroll
      for (int dt = 0; dt < 4; ++dt) {
        int d = dt * 16 + q15;
        bf16x8 vb = *(const bf16x8*)((const char*)Vs + d * 128 +
                                     (((4 * h + g) ^ (d & 7)) << 4));
        cacc[dt] = __builtin_amdgcn_mfma_f32_16x16x32_bf16(pa, vb, cacc[dt], 0, 0, 0);
      }
    }
  }

  float lf[4];
#pragma unroll
  for (int r = 0; r < 4; ++r) lf[r] = __shfl(l_run, 4 * g + r);
#pragma unroll
  for (int dt = 0; dt < 4; ++dt)
#pragma unroll
    for (int r = 0; r < 4; ++r) {
      float o = cacc[dt][r] / lf[r];
      ctx[(size_t)(qw + 4 * g + r) * ED + head * HD + dt * 16 + q15] = f2bf(o);
    }
}

extern "C" void kernel_launch(void* const* d_in, const int* in_sizes, int n_in,
                              void* d_out, int out_size, void* d_ws, size_t ws_size,
                              hipStream_t stream)
{
  const float* x    = (const float*)d_in[0];
  const float* mask = (const float*)d_in[1];
  const float* wq   = (const float*)d_in[2];
  const float* bq   = (const float*)d_in[3];
  const float* wk   = (const float*)d_in[4];
  const float* bk   = (const float*)d_in[5];
  const float* wv   = (const float*)d_in[6];
  const float* bv   = (const float*)d_in[7];
  const float* wo   = (const float*)d_in[8];
  const float* bo   = (const float*)d_in[9];
  float* out = (float*)d_out;

  char* ws = (char*)d_ws;
  unsigned short* xb    = (unsigned short*)(ws);                 // 6,291,456 B
  unsigned short* wb    = (unsigned short*)(ws + 6291456);       // 3,538,944 B
  unsigned short* wob   = (unsigned short*)(ws + 9830400);       // 1,179,648 B
  float*          biasc = (float*)(ws + 11010048);               // 9,216 B
  float*          qkvf  = (float*)(ws + 11019264);               // 37,748,736 B
  unsigned short* qrp   = (unsigned short*)(ws + 48768000);      // 6,291,456 B
  unsigned short* krp   = (unsigned short*)(ws + 55059456);      // 6,291,456 B
  unsigned short* vTp   = (unsigned short*)(ws + 61350912);      // 6,291,456 B
  unsigned short* ctxb  = (unsigned short*)(ws + 67642368);      // 6,291,456 B -> 73,933,824 total

  convert_kernel<<<21513, 256, 0, stream>>>(x, wq, wk, wv, wo, bq, bk, bv, xb, wb, wob, biasc);
  gemm_bf16nt<<<32 * 18, 256, 0, stream>>>(xb, wb, biasc, qkvf, 4096, 2304, 768, 2304);
  rope_kernel<<<6144, 256, 0, stream>>>(qkvf, qrp, 0, 0.125f);
  rope_kernel<<<6144, 256, 0, stream>>>(qkvf, krp, 768, 1.0f);
  vtrans_kernel<<<768, 256, 0, stream>>>(qkvf, vTp);
  attn_kernel<<<768, 256, 0, stream>>>(qrp, krp, vTp, mask, ctxb);
  gemm_bf16nt<<<32 * 6, 256, 0, stream>>>(ctxb, wob, bo, out, 4096, 768, 768, 768);
}